// Round 13
// baseline (54.216 us; speedup 1.0000x reference)
//
#include <hip/hip_runtime.h>
#include <hip/hip_bf16.h>
#include <math.h>

// B=16, H=W=256, 150 hidden channels, K=20 value-iteration steps.
//
// R13:
//  - conv_p_mfma: launch_bounds(256,2) -> 256 unified regs/wave. R12's (256,4)
//    showed VGPR_Count=48 vs ~90 live values + VALUBusy=100% => compiler put
//    accs/frags in AGPRs and issues v_accvgpr_read per EPI element (~3x instr
//    bloat). Issue-bound kernel: fewer instructions beats occupancy.
//  - mvprop_kernel: c = r - p*r precomputed; update = max(v, fma(p, m, c))
//    (2 ops, was 3). OOB rows: p=0, c=SENT -> update degenerates to v=v.
//  - pack_a_kernel: unchanged (R10/R12).

#define SENT -1e30f

typedef short short8 __attribute__((ext_vector_type(8)));
typedef float f32x16 __attribute__((ext_vector_type(16)));

__device__ __forceinline__ uint32_t pkbf(float lo, float hi) {
    uint32_t r;
    asm("v_cvt_pk_bf16_f32 %0, %1, %2" : "=v"(r) : "v"(lo), "v"(hi));
    return r;
}

__device__ __forceinline__ uint32_t bfu(float f) {
    __hip_bfloat16 h = __float2bfloat16(f);
    ushort u; __builtin_memcpy(&u, &h, 2);
    return (uint32_t)u;
}

__device__ __forceinline__ float max3f(float a, float b, float c) {
    return fmaxf(a, fmaxf(b, c));     // folds to v_max3_f32
}

// ---- setup: sign-partition + |Wp| scale + pack A fragments. 1x256.
__global__ void pack_a_kernel(const float* __restrict__ Wh,
                              const float* __restrict__ bh,
                              const float* __restrict__ Wp,
                              uint4* __restrict__ wsA)
{
    __shared__ int scan[256];
    const int tid = threadIdx.x;
    const bool valid = tid < 150;
    float wp = valid ? Wp[tid] : 0.f;
    bool pos = valid && (wp >= 0.f);
    bool neg = valid && (wp < 0.f);

    int v = (pos ? 1 : 0) | ((neg ? 1 : 0) << 16);
    scan[tid] = v;
    __syncthreads();
    for (int off = 1; off < 256; off <<= 1) {
        int x = scan[tid];
        int y = (tid >= off) ? scan[tid - off] : 0;
        __syncthreads();
        scan[tid] = x + y;
        __syncthreads();
    }
    int incl  = scan[tid];
    int total = scan[255];
    int P     = total & 0xffff;
    int rankPos = (incl & 0xffff) - (pos ? 1 : 0);
    int rankNeg = (incl >> 16)    - (neg ? 1 : 0);
    int Ppad  = (P + 31) & ~31;
    int nPosG = Ppad >> 5;
    int newidx = pos ? rankPos : (Ppad + rankNeg);

    if (tid < 384) wsA[tid] = make_uint4(0u, 0u, 0u, 0u);
    if (tid == 0)  ((uint32_t*)(wsA + 384))[0] = (uint32_t)nPosG;
    __syncthreads();

    if (valid) {
        float s  = fabsf(wp);          // |Wp|: sign handled by sg in epilogue
        float w0 = Wh[tid*9+0]*s, w1 = Wh[tid*9+1]*s, w2 = Wh[tid*9+2]*s;
        float w3 = Wh[tid*9+3]*s, w4 = Wh[tid*9+4]*s, w5 = Wh[tid*9+5]*s;
        float w6 = Wh[tid*9+6]*s, w7 = Wh[tid*9+7]*s, w8 = Wh[tid*9+8]*s;
        float bb = bh[tid]*s;
        int g = newidx >> 5, col0 = newidx & 31;
        uint4 q;
        q.x = (bfu(w1) << 16) | bfu(w0);
        q.y = (bfu(w3) << 16) | bfu(w2);
        q.z = (bfu(w5) << 16) | bfu(w4);
        q.w = (bfu(w7) << 16) | bfu(w6);
        wsA[g * 64 + col0] = q;                 // half 0: k=0..7
        q.x = (bfu(bb) << 16) | bfu(w8);        // half 1: k=8 tap, k=9 bias
        q.y = 0; q.z = 0; q.w = 0;
        wsA[g * 64 + 32 + col0] = q;
    }
}

#define EPI(D, SG)                                                           \
    S0 = fmaf(SG, fmaxf(D[0],  0.f), S0);                                    \
    S1 = fmaf(SG, fmaxf(D[1],  0.f), S1);                                    \
    S2 = fmaf(SG, fmaxf(D[2],  0.f), S2);                                    \
    S3 = fmaf(SG, fmaxf(D[3],  0.f), S3);                                    \
    S0 = fmaf(SG, fmaxf(D[4],  0.f), S0);                                    \
    S1 = fmaf(SG, fmaxf(D[5],  0.f), S1);                                    \
    S2 = fmaf(SG, fmaxf(D[6],  0.f), S2);                                    \
    S3 = fmaf(SG, fmaxf(D[7],  0.f), S3);                                    \
    S0 = fmaf(SG, fmaxf(D[8],  0.f), S0);                                    \
    S1 = fmaf(SG, fmaxf(D[9],  0.f), S1);                                    \
    S2 = fmaf(SG, fmaxf(D[10], 0.f), S2);                                    \
    S3 = fmaf(SG, fmaxf(D[11], 0.f), S3);                                    \
    S0 = fmaf(SG, fmaxf(D[12], 0.f), S0);                                    \
    S1 = fmaf(SG, fmaxf(D[13], 0.f), S1);                                    \
    S2 = fmaf(SG, fmaxf(D[14], 0.f), S2);                                    \
    S3 = fmaf(SG, fmaxf(D[15], 0.f), S3);

__global__ __launch_bounds__(256, 2) void conv_p_mfma(
    const float* __restrict__ image, const uint4* __restrict__ wsA,
    float* __restrict__ pout)
{
    const int tid  = threadIdx.x;
    const int wv   = tid >> 6;
    const int lane = tid & 63;
    const int half = lane >> 5;
    const int col0 = lane & 31;
    const int b    = blockIdx.z;
    const int y0   = blockIdx.y * 16 + wv * 4;   // wave owns rows y0..y0+3
    const int px   = blockIdx.x * 32 + col0;     // strip column
    const float* occ = image + (size_t)b * 131072;
    float* poutb = pout + (size_t)b * 65536;

    uint4 q0 = wsA[0*64+lane], q1 = wsA[1*64+lane], q2 = wsA[2*64+lane];
    uint4 q3 = wsA[3*64+lane], q4 = wsA[4*64+lane], q5 = wsA[5*64+lane];
    const int nPosG = (int)__builtin_amdgcn_readfirstlane(
        ((const uint32_t*)(wsA + 384))[0]);
    const float sg0 = (0 < nPosG) ? 1.f : -1.f;
    const float sg1 = (1 < nPosG) ? 1.f : -1.f;
    const float sg2 = (2 < nPosG) ? 1.f : -1.f;
    const float sg3 = (3 < nPosG) ? 1.f : -1.f;
    const float sg4 = (4 < nPosG) ? 1.f : -1.f;
    const float sg5 = (5 < nPosG) ? 1.f : -1.f;

    // taps for 4 pixel-rows: image rows y0-1 .. y0+4, cols px-1,px,px+1
    const bool x0ok = (px >= 1), x2ok = (px <= 254);
    float tm[6], tc[6], tp[6];
#pragma unroll
    for (int rr = 0; rr < 6; ++rr) {
        int yy = y0 - 1 + rr;
        bool yok = (yy >= 0) & (yy < 256);
        const float* base = occ + yy * 256;
        tm[rr] = (yok & x0ok) ? base[px - 1] : 0.f;
        tc[rr] =  yok         ? base[px]     : 0.f;
        tp[rr] = (yok & x2ok) ? base[px + 1] : 0.f;
    }

    union UA { uint4 q; short8 s; };
    UA u0, u1, u2, u3, u4, u5;
    u0.q = q0; u1.q = q1; u2.q = q2; u3.q = q3; u4.q = q4; u5.q = q5;

    const f32x16 kZero = {};
#pragma unroll
    for (int j = 0; j < 4; ++j) {
        float t0 = tm[j],   t1 = tc[j],   t2 = tp[j];
        float t3 = tm[j+1], t4 = tc[j+1], t5 = tp[j+1];
        float t6 = tm[j+2], t7 = tc[j+2], t8 = tp[j+2];

        union { uint32_t u[4]; short8 s; } bb;
        bb.u[0] = half ? pkbf(t8, 1.0f) : pkbf(t0, t1);
        bb.u[1] = half ? 0u : pkbf(t2, t3);
        bb.u[2] = half ? 0u : pkbf(t4, t5);
        bb.u[3] = half ? 0u : pkbf(t6, t7);
        short8 bfr = bb.s;

        float S0 = 0.f, S1 = 0.f, S2 = 0.f, S3 = 0.f;
        f32x16 dc, dn;
        dc = __builtin_amdgcn_mfma_f32_32x32x16_bf16(u0.s, bfr, kZero, 0, 0, 0);
        dn = __builtin_amdgcn_mfma_f32_32x32x16_bf16(u1.s, bfr, kZero, 0, 0, 0);
        EPI(dc, sg0)
        dc = __builtin_amdgcn_mfma_f32_32x32x16_bf16(u2.s, bfr, kZero, 0, 0, 0);
        EPI(dn, sg1)
        dn = __builtin_amdgcn_mfma_f32_32x32x16_bf16(u3.s, bfr, kZero, 0, 0, 0);
        EPI(dc, sg2)
        dc = __builtin_amdgcn_mfma_f32_32x32x16_bf16(u4.s, bfr, kZero, 0, 0, 0);
        EPI(dn, sg3)
        dn = __builtin_amdgcn_mfma_f32_32x32x16_bf16(u5.s, bfr, kZero, 0, 0, 0);
        EPI(dc, sg4)
        EPI(dn, sg5)

        float s = (S0 + S1) + (S2 + S3);
        s += __shfl_xor(s, 32);   // combine the two half-wave channel sets

        float p = 1.f / (1.f + __expf(-s));
        if (!half)
            poutb[(y0 + j) * 256 + px] = p;
    }
}

__global__ __launch_bounds__(512, 2) void mvprop_kernel(
    const float* __restrict__ image, const float* __restrict__ pbuf,
    float* __restrict__ out)
{
    const int tid  = threadIdx.x;
    const int w    = tid >> 6;          // wave 0..7, owns ext rows 7w..7w+6
    const int lane = tid & 63;          // lane owns cols 4*lane..4*lane+3
    const int b    = blockIdx.z;
    const int gy0  = blockIdx.y * 16 - 20;   // ext row 0 -> global row gy0
    const int x4   = lane * 4;

    const float* rimg = image + (size_t)b * 131072 + 65536;  // channel 1
    const float* pp   = pbuf  + (size_t)b * 65536;

    // c = r - p*r; update is v = max(v, fma(p, m, c)). OOB: p=0, c=SENT.
    float v[7][4], c[7][4], p[7][4];
#pragma unroll
    for (int i = 0; i < 7; ++i) {
        int gy = gy0 + w * 7 + i;
        if (gy >= 0 && gy < 256) {
            float4 rv = *(const float4*)&rimg[gy * 256 + x4];
            float4 pv = *(const float4*)&pp[gy * 256 + x4];
            p[i][0] = pv.x; p[i][1] = pv.y; p[i][2] = pv.z; p[i][3] = pv.w;
            c[i][0] = fmaf(-pv.x, rv.x, rv.x);
            c[i][1] = fmaf(-pv.y, rv.y, rv.y);
            c[i][2] = fmaf(-pv.z, rv.z, rv.z);
            c[i][3] = fmaf(-pv.w, rv.w, rv.w);
            v[i][0] = rv.x; v[i][1] = rv.y; v[i][2] = rv.z; v[i][3] = rv.w;
        } else {
            c[i][0] = c[i][1] = c[i][2] = c[i][3] = SENT;
            p[i][0] = p[i][1] = p[i][2] = p[i][3] = 0.f;
            v[i][0] = v[i][1] = v[i][2] = v[i][3] = SENT;
        }
    }

    __shared__ float4 gT[2][8][64];
    __shared__ float4 gB[2][8][64];

    for (int t = 0; t < 20; ++t) {
        int bf = t & 1;
        gT[bf][w][lane] = make_float4(v[0][0], v[0][1], v[0][2], v[0][3]);
        gB[bf][w][lane] = make_float4(v[6][0], v[6][1], v[6][2], v[6][3]);
        __syncthreads();
        float4 abv = (w > 0) ? gB[bf][w - 1][lane]
                             : make_float4(SENT, SENT, SENT, SENT);
        float4 blw = (w < 7) ? gT[bf][w + 1][lane]
                             : make_float4(SENT, SENT, SENT, SENT);

        float pv0 = abv.x, pv1 = abv.y, pv2 = abv.z, pv3 = abv.w;
#pragma unroll
        for (int i = 0; i < 7; ++i) {
            float c0 = v[i][0], c1 = v[i][1], c2 = v[i][2], c3 = v[i][3];
            float n0, n1, n2, n3;
            if (i < 6) { n0 = v[i+1][0]; n1 = v[i+1][1]; n2 = v[i+1][2]; n3 = v[i+1][3]; }
            else       { n0 = blw.x;     n1 = blw.y;     n2 = blw.z;     n3 = blw.w;     }
            float vm0 = max3f(pv0, c0, n0);
            float vm1 = max3f(pv1, c1, n1);
            float vm2 = max3f(pv2, c2, n2);
            float vm3 = max3f(pv3, c3, n3);
            float lL = __shfl_up(vm3, 1);
            lL = (lane == 0) ? SENT : lL;
            float rR = __shfl_down(vm0, 1);
            rR = (lane == 63) ? SENT : rR;
            float h0 = max3f(lL,  vm0, vm1);
            float h1 = max3f(vm0, vm1, vm2);
            float h2 = max3f(vm1, vm2, vm3);
            float h3 = max3f(vm2, vm3, rR);
            v[i][0] = fmaxf(c0, fmaf(p[i][0], h0, c[i][0]));
            v[i][1] = fmaxf(c1, fmaf(p[i][1], h1, c[i][1]));
            v[i][2] = fmaxf(c2, fmaf(p[i][2], h2, c[i][2]));
            v[i][3] = fmaxf(c3, fmaf(p[i][3], h3, c[i][3]));
            pv0 = c0; pv1 = c1; pv2 = c2; pv3 = c3;
        }
    }

    const float* occ = image + (size_t)b * 131072;
#pragma unroll
    for (int i = 0; i < 7; ++i) {
        int e = w * 7 + i;
        if (e >= 20 && e < 36) {
            int gy = gy0 + e;
            float4 ov = *(const float4*)&occ[gy * 256 + x4];
            float4 o;
            o.x = (ov.x > 0.49f) ? v[i][0] : -1.f;
            o.y = (ov.y > 0.49f) ? v[i][1] : -1.f;
            o.z = (ov.z > 0.49f) ? v[i][2] : -1.f;
            o.w = (ov.w > 0.49f) ? v[i][3] : -1.f;
            *(float4*)&out[(size_t)b * 65536 + gy * 256 + x4] = o;
        }
    }
}

extern "C" void kernel_launch(void* const* d_in, const int* in_sizes, int n_in,
                              void* d_out, int out_size, void* d_ws, size_t ws_size,
                              hipStream_t stream) {
    const float* image = (const float*)d_in[0];  // (16,2,256,256)
    const float* Wh    = (const float*)d_in[1];  // (150,1,3,3)
    const float* bh    = (const float*)d_in[2];  // (150,)
    const float* Wp    = (const float*)d_in[3];  // (1,150,1,1)
    float* out  = (float*)d_out;                 // (16,1,256,256) f32
    float* pbuf = (float*)d_ws;                  // 4 MB scratch for p
    uint4* wsA  = (uint4*)((char*)d_ws + (4 << 20));  // A-fragments + header

    pack_a_kernel<<<1, 256, 0, stream>>>(Wh, bh, Wp, wsA);
    conv_p_mfma<<<dim3(8, 16, 16), dim3(256), 0, stream>>>(image, wsA, pbuf);
    mvprop_kernel<<<dim3(1, 16, 16), dim3(512), 0, stream>>>(image, pbuf, out);
}